// Round 7
// baseline (2060.924 us; speedup 1.0000x reference)
//
#include <hip/hip_runtime.h>

// ---------------------------------------------------------------------------
// GraphSAGE 2-layer hetero (R=2) + edge dot scorer.  Round 7:
//  * transform-then-aggregate kept (GEMM y=xWn, z=xWc+b first).
//  * aggregation rebuilt: one block per 32-node dst bucket, EDGE-PARALLEL
//    gathers (quarter/eighth-wave per edge, uint4 16B/lane, many independent
//    rows in flight) scattering into an LDS f32 accumulator via LDS
//    atomicAdd (padded stride to bound bank conflicts). Degrees/inv computed
//    in-block from the bucket-grouped (src,dst) pairs -> the bucket_csr pass
//    and csr/off arrays are deleted.
//  * CSR build = count + scan + partition only (staging pairs, dedicated
//    buffer, no aliasing with z1).
// ---------------------------------------------------------------------------

#define BW 32             // nodes per dst bucket (pow2); d>>5
#define NBK_MAX 2048      // supports N <= 65536
#define EPB 8192          // edges per block in radix passes

__device__ __forceinline__ unsigned short f2bf(float f) {
    unsigned u = __float_as_uint(f);
    unsigned r = u + 0x7FFFu + ((u >> 16) & 1u);
    return (unsigned short)(r >> 16);
}
__device__ __forceinline__ unsigned pack2(float a, float b) {
    return (unsigned)f2bf(a) | ((unsigned)f2bf(b) << 16);
}
__device__ __forceinline__ float bflo(unsigned v) { return __uint_as_float(v << 16); }
__device__ __forceinline__ float bfhi(unsigned v) { return __uint_as_float(v & 0xFFFF0000u); }

// ---- radix pass A: per-(r,bucket) counts --------------------------------
__global__ __launch_bounds__(256) void
bucket_count_kernel(const int* __restrict__ edges, int* __restrict__ bcnt,
                    int NBK, int E)
{
    __shared__ int cnt[2 * NBK_MAX];
    const int rbT = 2 * NBK;
    const int t = threadIdx.x;
    for (int k = t; k < rbT; k += 256) cnt[k] = 0;
    __syncthreads();
    long long start = (long long)blockIdx.x * EPB;
    long long twoE = 2LL * E;
    for (int u = 0; u < EPB / 256; ++u) {
        long long idx = start + u * 256 + t;
        if (idx < twoE) {
            int r = idx >= E;
            int e = (int)(idx - (long long)r * E);
            int d = edges[(size_t)r * 2 * E + E + e];
            atomicAdd(&cnt[r * NBK + (d >> 5)], 1);
        }
    }
    __syncthreads();
    for (int k = t; k < rbT; k += 256)
        if (cnt[k]) atomicAdd(&bcnt[k], cnt[k]);
}

// ---- radix pass B: exclusive scan of bucket counts (one block, chunked) --
__global__ __launch_bounds__(1024) void
bucket_scan_kernel(const int* __restrict__ bcnt, int* __restrict__ bko,
                   int rbT, int twoE)
{
    __shared__ int sm[1024];
    __shared__ int carry;
    int t = threadIdx.x;
    if (t == 0) carry = 0;
    __syncthreads();
    for (int base = 0; base < rbT; base += 1024) {
        int i = base + t;
        int v = (i < rbT) ? bcnt[i] : 0;
        sm[t] = v;
        __syncthreads();
        for (int s = 1; s < 1024; s <<= 1) {
            int u = (t >= s) ? sm[t - s] : 0;
            __syncthreads();
            sm[t] += u;
            __syncthreads();
        }
        if (i < rbT) bko[i] = carry + sm[t] - v;
        __syncthreads();
        if (t == 1023) carry += sm[1023];
        __syncthreads();
    }
    if (t == 0) bko[rbT] = twoE;
}

// ---- radix pass C: partition into bucket-grouped (src,dst) pairs --------
__global__ __launch_bounds__(256) void
partition_kernel(const int* __restrict__ edges, const int* __restrict__ bko,
                 int* __restrict__ gcur, uint2* __restrict__ staging,
                 int NBK, int E)
{
    __shared__ int cnt[2 * NBK_MAX];
    __shared__ int base[2 * NBK_MAX];
    const int rbT = 2 * NBK;
    const int t = threadIdx.x;
    for (int k = t; k < rbT; k += 256) cnt[k] = 0;
    __syncthreads();
    long long start = (long long)blockIdx.x * EPB;
    long long twoE = 2LL * E;
    for (int u = 0; u < EPB / 256; ++u) {
        long long idx = start + u * 256 + t;
        if (idx < twoE) {
            int r = idx >= E;
            int e = (int)(idx - (long long)r * E);
            int d = edges[(size_t)r * 2 * E + E + e];
            atomicAdd(&cnt[r * NBK + (d >> 5)], 1);
        }
    }
    __syncthreads();
    for (int k = t; k < rbT; k += 256) {
        int c0 = cnt[k];
        if (c0) base[k] = bko[k] + atomicAdd(&gcur[k], c0);
        cnt[k] = 0;
    }
    __syncthreads();
    for (int u = 0; u < EPB / 256; ++u) {
        long long idx = start + u * 256 + t;
        if (idx < twoE) {
            int r = idx >= E;
            int e = (int)(idx - (long long)r * E);
            int s = edges[(size_t)r * 2 * E + e];
            int d = edges[(size_t)r * 2 * E + E + e];
            int rb = r * NBK + (d >> 5);
            int pos = atomicAdd(&cnt[rb], 1);
            staging[(size_t)base[rb] + pos] = make_uint2((unsigned)s, (unsigned)d);
        }
    }
}

// ---- f32 -> bf16 --------------------------------------------------------
__global__ void cvt_kernel(const float* __restrict__ in,
                           unsigned short* __restrict__ o, int n4)
{
    int t = blockIdx.x * blockDim.x + threadIdx.x;
    if (t >= n4) return;
    float4 v = ((const float4*)in)[t];
    ushort4 r;
    r.x = f2bf(v.x); r.y = f2bf(v.y); r.z = f2bf(v.z); r.w = f2bf(v.w);
    ((ushort4*)o)[t] = r;
}

// ---- Wself/bias combine --------------------------------------------------
__global__ void prep_kernel(const float* __restrict__ Ws1, const float* __restrict__ b1,
                            const float* __restrict__ Ws2, const float* __restrict__ b2,
                            float* __restrict__ Wc1, float* __restrict__ bc1,
                            float* __restrict__ Wc2, float* __restrict__ bc2)
{
    int t = blockIdx.x * blockDim.x + threadIdx.x;
    if (t < 16384) Wc1[t] = Ws1[t] + Ws1[16384 + t];
    if (t < 128)   bc1[t] = b1[t] + b1[128 + t];
    if (t < 8192)  Wc2[t] = Ws2[t] + Ws2[8192 + t];
    if (t < 64)    bc2[t] = b2[t] + b2[64 + t];
}

// ---- GEMM: blockIdx.y selects {z=A@Wz+bias (f32), ya=A@Wa, yb=A@Wb (bf16)}
template<int BN>
__global__ __launch_bounds__(256) void
gemm_kernel(const unsigned short* __restrict__ Ab,
            const float* __restrict__ Wz, const float* __restrict__ Wa,
            const float* __restrict__ Wb, const float* __restrict__ bias,
            float* __restrict__ zf,
            unsigned short* __restrict__ ya, unsigned short* __restrict__ yb,
            int N)
{
    constexpr int TCOLS = BN / 4;
    constexpr int TROWS = 256 / TCOLS;
    constexpr int BM = TROWS * 8;
    constexpr int BK = 32;
    constexpr int F4_PER_WROW = BN / 4;

    __shared__ float As[BK][BM + 4];
    __shared__ float Wsm[BK][BN];

    const int sel = blockIdx.y;
    const float* W = (sel == 0) ? Wz : ((sel == 1) ? Wa : Wb);

    const int tid = threadIdx.x;
    const int tc = tid % TCOLS;
    const int tr = tid / TCOLS;
    const int j0 = tc * 4;
    const int i0 = tr * 8;
    const int rowBase = blockIdx.x * BM;

    float acc[8][4];
#pragma unroll
    for (int r = 0; r < 8; ++r)
#pragma unroll
        for (int c = 0; c < 4; ++c) acc[r][c] = 0.0f;

    for (int k0 = 0; k0 < 128; k0 += BK) {
        constexpr int A_U4 = BM * 4;
#pragma unroll
        for (int p = 0; p < A_U4 / 256; ++p) {
            int q = tid + p * 256;
            int row = q >> 2;
            int part = q & 3;
            int kq = part * 8;
            int rg = rowBase + row;
            if (rg >= N) rg = N - 1;
            uint4 v = *(const uint4*)(Ab + (size_t)rg * 128 + k0 + kq);
            As[kq + 0][row] = bflo(v.x);
            As[kq + 1][row] = bfhi(v.x);
            As[kq + 2][row] = bflo(v.y);
            As[kq + 3][row] = bfhi(v.y);
            As[kq + 4][row] = bflo(v.z);
            As[kq + 5][row] = bfhi(v.z);
            As[kq + 6][row] = bflo(v.w);
            As[kq + 7][row] = bfhi(v.w);
        }
        constexpr int W_F4 = BK * F4_PER_WROW;
#pragma unroll
        for (int p = 0; p < W_F4 / 256; ++p) {
            int q = tid + p * 256;
            int rk = q / F4_PER_WROW;
            int jq = (q % F4_PER_WROW) * 4;
            float4 v = *(const float4*)(W + (size_t)(k0 + rk) * BN + jq);
            *(float4*)&Wsm[rk][jq] = v;
        }
        __syncthreads();

#pragma unroll 8
        for (int k = 0; k < BK; ++k) {
            float4 w = *(const float4*)&Wsm[k][j0];
            const float* ap = &As[k][i0];
            float4 a0 = *(const float4*)(ap);
            float4 a1 = *(const float4*)(ap + 4);
            float av[8] = {a0.x, a0.y, a0.z, a0.w, a1.x, a1.y, a1.z, a1.w};
#pragma unroll
            for (int r = 0; r < 8; ++r) {
                acc[r][0] = fmaf(av[r], w.x, acc[r][0]);
                acc[r][1] = fmaf(av[r], w.y, acc[r][1]);
                acc[r][2] = fmaf(av[r], w.z, acc[r][2]);
                acc[r][3] = fmaf(av[r], w.w, acc[r][3]);
            }
        }
        __syncthreads();
    }

    float4 bv = make_float4(0.f, 0.f, 0.f, 0.f);
    if (sel == 0) bv = *(const float4*)(bias + j0);
    unsigned short* ob = (sel == 1) ? ya : yb;
#pragma unroll
    for (int r = 0; r < 8; ++r) {
        int row = rowBase + i0 + r;
        if (row >= N) break;
        float4 o;
        o.x = acc[r][0] + bv.x;
        o.y = acc[r][1] + bv.y;
        o.z = acc[r][2] + bv.z;
        o.w = acc[r][3] + bv.w;
        if (sel == 0) {
            *(float4*)(zf + (size_t)row * BN + j0) = o;
        } else {
            ushort4 u;
            u.x = f2bf(o.x); u.y = f2bf(o.y); u.z = f2bf(o.z); u.w = f2bf(o.w);
            *(ushort4*)(ob + (size_t)row * BN + j0) = u;
        }
    }
}

// ---- agg L1: block per 32-node bucket, quarter-wave per edge -------------
// h1 = relu(z1 + mean0(y0) + mean1(y1)) -> bf16 [N,128]
__global__ __launch_bounds__(256) void
agg1_kernel(const unsigned short* __restrict__ y0,
            const unsigned short* __restrict__ y1,
            const float* __restrict__ z1,
            const uint2* __restrict__ staging,
            const int* __restrict__ bko,
            unsigned short* __restrict__ h1b,
            int NBK, int N)
{
    __shared__ float sacc[BW][129];      // stride 129: 129%32==1 spreads banks
    __shared__ float inv[2 * BW];
    __shared__ int hist[2 * BW];
    const int b = blockIdx.x;
    const int node0 = b * BW;
    const int t = threadIdx.x;

    for (int i = t; i < BW * 129; i += 256) ((float*)sacc)[i] = 0.f;
    if (t < 2 * BW) hist[t] = 0;
    __syncthreads();

    const int s0 = bko[b],       e0 = bko[b + 1];
    const int s1 = bko[NBK + b], e1 = bko[NBK + b + 1];
    for (int j = s0 + t; j < e0; j += 256) atomicAdd(&hist[(int)staging[j].y - node0], 1);
    for (int j = s1 + t; j < e1; j += 256) atomicAdd(&hist[BW + (int)staging[j].y - node0], 1);
    __syncthreads();
    if (t < 2 * BW) inv[t] = 1.0f / fmaxf((float)hist[t], 1.0f);
    __syncthreads();

    const int qid = t >> 4;   // 0..15 quarter-wave id within block
    const int l = t & 15;     // lane within quarter: cols 8l..8l+7

    for (int j = s0 + qid; j < e0; j += 16) {
        uint2 pr = staging[j];
        int dl = (int)pr.y - node0;
        float sc = inv[dl];
        uint4 v = *(const uint4*)(y0 + (size_t)pr.x * 128 + l * 8);
        float* ap = &sacc[dl][l * 8];
        atomicAdd(ap + 0, bflo(v.x) * sc);
        atomicAdd(ap + 1, bfhi(v.x) * sc);
        atomicAdd(ap + 2, bflo(v.y) * sc);
        atomicAdd(ap + 3, bfhi(v.y) * sc);
        atomicAdd(ap + 4, bflo(v.z) * sc);
        atomicAdd(ap + 5, bfhi(v.z) * sc);
        atomicAdd(ap + 6, bflo(v.w) * sc);
        atomicAdd(ap + 7, bfhi(v.w) * sc);
    }
    for (int j = s1 + qid; j < e1; j += 16) {
        uint2 pr = staging[j];
        int dl = (int)pr.y - node0;
        float sc = inv[BW + dl];
        uint4 v = *(const uint4*)(y1 + (size_t)pr.x * 128 + l * 8);
        float* ap = &sacc[dl][l * 8];
        atomicAdd(ap + 0, bflo(v.x) * sc);
        atomicAdd(ap + 1, bfhi(v.x) * sc);
        atomicAdd(ap + 2, bflo(v.y) * sc);
        atomicAdd(ap + 3, bfhi(v.y) * sc);
        atomicAdd(ap + 4, bflo(v.z) * sc);
        atomicAdd(ap + 5, bfhi(v.z) * sc);
        atomicAdd(ap + 6, bflo(v.w) * sc);
        atomicAdd(ap + 7, bfhi(v.w) * sc);
    }
    __syncthreads();

    for (int idx = t; idx < BW * 64; idx += 256) {
        int n = idx >> 6;
        int cw = idx & 63;
        int gn = node0 + n;
        if (gn < N) {
            float2 z = *(const float2*)(z1 + (size_t)gn * 128 + cw * 2);
            float hx = fmaxf(z.x + sacc[n][cw * 2],     0.0f);
            float hy = fmaxf(z.y + sacc[n][cw * 2 + 1], 0.0f);
            *(unsigned*)(h1b + (size_t)gn * 128 + cw * 2) = pack2(hx, hy);
        }
    }
}

// ---- agg L2: block per bucket, eighth-wave per edge, 64 cols -------------
// h2 = z2 + mean0(t0) + mean1(t1) -> bf16 [N,64]
__global__ __launch_bounds__(256) void
agg2_kernel(const unsigned short* __restrict__ t0,
            const unsigned short* __restrict__ t1,
            const float* __restrict__ z2,
            const uint2* __restrict__ staging,
            const int* __restrict__ bko,
            unsigned short* __restrict__ h2b,
            int NBK, int N)
{
    __shared__ float sacc[BW][65];
    __shared__ float inv[2 * BW];
    __shared__ int hist[2 * BW];
    const int b = blockIdx.x;
    const int node0 = b * BW;
    const int t = threadIdx.x;

    for (int i = t; i < BW * 65; i += 256) ((float*)sacc)[i] = 0.f;
    if (t < 2 * BW) hist[t] = 0;
    __syncthreads();

    const int s0 = bko[b],       e0 = bko[b + 1];
    const int s1 = bko[NBK + b], e1 = bko[NBK + b + 1];
    for (int j = s0 + t; j < e0; j += 256) atomicAdd(&hist[(int)staging[j].y - node0], 1);
    for (int j = s1 + t; j < e1; j += 256) atomicAdd(&hist[BW + (int)staging[j].y - node0], 1);
    __syncthreads();
    if (t < 2 * BW) inv[t] = 1.0f / fmaxf((float)hist[t], 1.0f);
    __syncthreads();

    const int eid = t >> 3;   // 0..31 eighth-wave id
    const int l = t & 7;      // cols 8l..8l+7

    for (int j = s0 + eid; j < e0; j += 32) {
        uint2 pr = staging[j];
        int dl = (int)pr.y - node0;
        float sc = inv[dl];
        uint4 v = *(const uint4*)(t0 + (size_t)pr.x * 64 + l * 8);
        float* ap = &sacc[dl][l * 8];
        atomicAdd(ap + 0, bflo(v.x) * sc);
        atomicAdd(ap + 1, bfhi(v.x) * sc);
        atomicAdd(ap + 2, bflo(v.y) * sc);
        atomicAdd(ap + 3, bfhi(v.y) * sc);
        atomicAdd(ap + 4, bflo(v.z) * sc);
        atomicAdd(ap + 5, bfhi(v.z) * sc);
        atomicAdd(ap + 6, bflo(v.w) * sc);
        atomicAdd(ap + 7, bfhi(v.w) * sc);
    }
    for (int j = s1 + eid; j < e1; j += 32) {
        uint2 pr = staging[j];
        int dl = (int)pr.y - node0;
        float sc = inv[BW + dl];
        uint4 v = *(const uint4*)(t1 + (size_t)pr.x * 64 + l * 8);
        float* ap = &sacc[dl][l * 8];
        atomicAdd(ap + 0, bflo(v.x) * sc);
        atomicAdd(ap + 1, bfhi(v.x) * sc);
        atomicAdd(ap + 2, bflo(v.y) * sc);
        atomicAdd(ap + 3, bfhi(v.y) * sc);
        atomicAdd(ap + 4, bflo(v.z) * sc);
        atomicAdd(ap + 5, bfhi(v.z) * sc);
        atomicAdd(ap + 6, bflo(v.w) * sc);
        atomicAdd(ap + 7, bfhi(v.w) * sc);
    }
    __syncthreads();

    for (int idx = t; idx < BW * 32; idx += 256) {
        int n = idx >> 5;
        int cw = idx & 31;
        int gn = node0 + n;
        if (gn < N) {
            float2 z = *(const float2*)(z2 + (size_t)gn * 64 + cw * 2);
            float hx = z.x + sacc[n][cw * 2];
            float hy = z.y + sacc[n][cw * 2 + 1];
            *(unsigned*)(h2b + (size_t)gn * 64 + cw * 2) = pack2(hx, hy);
        }
    }
}

// ---- score: 8 lanes/edge, coalesced 128B rows, shfl reduce ---------------
__global__ __launch_bounds__(256) void
score_kernel(const unsigned short* __restrict__ h, // [N,64] bf16
             const int* __restrict__ src, const int* __restrict__ dst,
             float* __restrict__ out, int E)
{
    int t = blockIdx.x * blockDim.x + threadIdx.x;
    int e = t >> 3;
    int c = t & 7;
    if (e >= E) return;
    uint4 va = *(const uint4*)(h + (size_t)src[e] * 64 + c * 8);
    uint4 vb = *(const uint4*)(h + (size_t)dst[e] * 64 + c * 8);
    float s = 0.0f;
    s = fmaf(bflo(va.x), bflo(vb.x), s);
    s = fmaf(bfhi(va.x), bfhi(vb.x), s);
    s = fmaf(bflo(va.y), bflo(vb.y), s);
    s = fmaf(bfhi(va.y), bfhi(vb.y), s);
    s = fmaf(bflo(va.z), bflo(vb.z), s);
    s = fmaf(bfhi(va.z), bfhi(vb.z), s);
    s = fmaf(bflo(va.w), bflo(vb.w), s);
    s = fmaf(bfhi(va.w), bfhi(vb.w), s);
    s += __shfl_xor(s, 1);
    s += __shfl_xor(s, 2);
    s += __shfl_xor(s, 4);
    if (c == 0) out[e] = s;
}

extern "C" void kernel_launch(void* const* d_in, const int* in_sizes, int n_in,
                              void* d_out, int out_size, void* d_ws, size_t ws_size,
                              hipStream_t stream)
{
    const float* x     = (const float*)d_in[0];
    const int*   edges = (const int*)d_in[1];
    const int*   neg   = (const int*)d_in[2];
    const float* Wn1   = (const float*)d_in[3];
    const float* Ws1   = (const float*)d_in[4];
    const float* b1    = (const float*)d_in[5];
    const float* Wn2   = (const float*)d_in[6];
    const float* Ws2   = (const float*)d_in[7];
    const float* b2    = (const float*)d_in[8];
    float* out = (float*)d_out;

    const int Fin = 128, R = 2;
    const int N  = in_sizes[0] / Fin;        // 50000
    const int E  = in_sizes[1] / (R * 2);    // 800000
    const int En = in_sizes[2] / 2;          // 800000
    const int twoE = 2 * E;
    const int NBK = (N + BW - 1) / BW;       // 1563
    const int rbT = 2 * NBK;

    // ---- workspace layout ----
    float* ws = (float*)d_ws;
    float* z1 = ws;                                    // [N,128] f32 (z2 reuses)
    unsigned short* y0  = (unsigned short*)(z1 + (size_t)N * 128);  // [N,128] bf16 (t0 reuses)
    unsigned short* y1  = y0 + (size_t)N * 128;        // [N,128] bf16 (t1 + h2b reuse)
    unsigned short* xb  = y1 + (size_t)N * 128;        // [N,128] bf16
    unsigned short* h1b = xb + (size_t)N * 128;        // [N,128] bf16
    uint2* staging = (uint2*)(h1b + (size_t)N * 128);  // [2E] pairs (dedicated)
    float* Wc1 = (float*)(staging + (size_t)twoE);     // [128,128]
    float* bc1 = Wc1 + 16384;
    float* Wc2 = bc1 + 128;                            // [128,64]
    float* bc2 = Wc2 + 8192;
    int* bcnt = (int*)(bc2 + 64);                      // [2*NBK_MAX]
    int* gcur = bcnt + 2 * NBK_MAX;                    // [2*NBK_MAX]
    int* bko  = gcur + 2 * NBK_MAX;                    // [2*NBK_MAX+1]

    float* z2 = z1;                                    // [N,64] f32
    unsigned short* t0 = y0;                           // [N,64] bf16
    unsigned short* t1 = y1;                           // [N,64] bf16
    unsigned short* h2b = y1 + (size_t)N * 64;         // [N,64] bf16

    const int BS = 256;
    const int edge_blocks = (twoE + EPB - 1) / EPB;

    // ---- bucket build: count + scan + partition ----
    hipMemsetAsync(bcnt, 0, (size_t)4 * NBK_MAX * sizeof(int), stream);
    bucket_count_kernel<<<edge_blocks, BS, 0, stream>>>(edges, bcnt, NBK, E);
    bucket_scan_kernel<<<1, 1024, 0, stream>>>(bcnt, bko, rbT, twoE);
    partition_kernel<<<edge_blocks, BS, 0, stream>>>(edges, bko, gcur, staging, NBK, E);

    // ---- prep ----
    cvt_kernel<<<(N * 32 + BS - 1) / BS, BS, 0, stream>>>(x, xb, N * 32);
    prep_kernel<<<(16384 + BS - 1) / BS, BS, 0, stream>>>(Ws1, b1, Ws2, b2, Wc1, bc1, Wc2, bc2);

    // ---- Layer 1: transform then aggregate ----
    {
        dim3 g((N + 63) / 64, 3);
        gemm_kernel<128><<<g, BS, 0, stream>>>(xb, Wc1, Wn1, Wn1 + 16384, bc1,
                                               z1, y0, y1, N);
    }
    agg1_kernel<<<NBK, BS, 0, stream>>>(y0, y1, z1, staging, bko, h1b, NBK, N);

    // ---- Layer 2 ----
    {
        dim3 g((N + 127) / 128, 3);
        gemm_kernel<64><<<g, BS, 0, stream>>>(h1b, Wc2, Wn2, Wn2 + 8192, bc2,
                                              z2, t0, t1, N);
    }
    agg2_kernel<<<NBK, BS, 0, stream>>>(t0, t1, z2, staging, bko, h2b, NBK, N);

    // ---- Scores ----
    score_kernel<<<(E * 8 + BS - 1) / BS, BS, 0, stream>>>(h2b, edges, edges + E, out, E);
    score_kernel<<<(En * 8 + BS - 1) / BS, BS, 0, stream>>>(h2b, neg, neg + En, out + E, En);
}

// Round 8
// 392.731 us; speedup vs baseline: 5.2477x; 5.2477x over previous
//
#include <hip/hip_runtime.h>

// ---------------------------------------------------------------------------
// GraphSAGE 2-layer hetero (R=2) + edge dot scorer.  Round 8:
//  * aggregation reverted to round-6 wave-per-node register-sum gathers
//    (round-7 LDS-atomic scatter serialized: 326k bank-conflict cycles,
//    14x regression). agg1 unrolled x8, agg2 unrolled x4 per half (was the
//    latency-bound laggard at 1.0 TB/s vs the 2.4 TB/s gather ceiling).
//  * GEMMs moved to MFMA (mfma_f32_16x16x32_bf16): wave = 16 rows x BN cols,
//    A-frag per-lane loads A[m=lane&15][k=quad*8+j] (16B/lane) direct from
//    global; B = bf16 W^T rows (B^T form, same as verified gemm_bt);
//    C/D layout col=lane&15, row=quad*4+reg; LDS-transpose epilogue for
//    coalesced f32/bf16 stores.
//  * CSR build (BW=128 buckets: count/scan/partition/bucket_csr) = round 6.
// ---------------------------------------------------------------------------

#define BW 128            // nodes per radix bucket (pow2)
#define NBK_MAX 1024
#define EPB 8192          // edges per block in radix passes

typedef __attribute__((ext_vector_type(8))) short bf16x8;
typedef __attribute__((ext_vector_type(4))) float floatx4;

__device__ __forceinline__ unsigned short f2bf(float f) {
    unsigned u = __float_as_uint(f);
    unsigned r = u + 0x7FFFu + ((u >> 16) & 1u);
    return (unsigned short)(r >> 16);
}
__device__ __forceinline__ unsigned pack2(float a, float b) {
    return (unsigned)f2bf(a) | ((unsigned)f2bf(b) << 16);
}
__device__ __forceinline__ float bflo(unsigned v) { return __uint_as_float(v << 16); }
__device__ __forceinline__ float bfhi(unsigned v) { return __uint_as_float(v & 0xFFFF0000u); }

// ---- radix pass A: per-(r,bucket) counts --------------------------------
__global__ __launch_bounds__(256) void
bucket_count_kernel(const int* __restrict__ edges, int* __restrict__ bcnt,
                    int NBK, int E)
{
    __shared__ int cnt[2 * NBK_MAX];
    const int rbT = 2 * NBK;
    const int t = threadIdx.x;
    for (int k = t; k < rbT; k += 256) cnt[k] = 0;
    __syncthreads();
    long long start = (long long)blockIdx.x * EPB;
    long long twoE = 2LL * E;
    for (int u = 0; u < EPB / 256; ++u) {
        long long idx = start + u * 256 + t;
        if (idx < twoE) {
            int r = idx >= E;
            int e = (int)(idx - (long long)r * E);
            int d = edges[(size_t)r * 2 * E + E + e];
            atomicAdd(&cnt[r * NBK + (d >> 7)], 1);
        }
    }
    __syncthreads();
    for (int k = t; k < rbT; k += 256)
        if (cnt[k]) atomicAdd(&bcnt[k], cnt[k]);
}

// ---- radix pass B: exclusive scan of bucket counts ----------------------
__global__ __launch_bounds__(1024) void
bucket_scan_kernel(const int* __restrict__ bcnt, int* __restrict__ bko,
                   int rbT, int twoE)
{
    __shared__ int sm[1024];
    int t = threadIdx.x;
    int v = (t < rbT) ? bcnt[t] : 0;
    sm[t] = v;
    __syncthreads();
    for (int s = 1; s < 1024; s <<= 1) {
        int u = (t >= s) ? sm[t - s] : 0;
        __syncthreads();
        sm[t] += u;
        __syncthreads();
    }
    if (t < rbT) bko[t] = sm[t] - v;
    if (t == 0) bko[rbT] = twoE;
}

// ---- radix pass C: partition into bucket-grouped (src,dst) pairs --------
__global__ __launch_bounds__(256) void
partition_kernel(const int* __restrict__ edges, const int* __restrict__ bko,
                 int* __restrict__ gcur, uint2* __restrict__ staging,
                 int NBK, int E)
{
    __shared__ int cnt[2 * NBK_MAX];
    __shared__ int base[2 * NBK_MAX];
    const int rbT = 2 * NBK;
    const int t = threadIdx.x;
    for (int k = t; k < rbT; k += 256) cnt[k] = 0;
    __syncthreads();
    long long start = (long long)blockIdx.x * EPB;
    long long twoE = 2LL * E;
    for (int u = 0; u < EPB / 256; ++u) {
        long long idx = start + u * 256 + t;
        if (idx < twoE) {
            int r = idx >= E;
            int e = (int)(idx - (long long)r * E);
            int d = edges[(size_t)r * 2 * E + E + e];
            atomicAdd(&cnt[r * NBK + (d >> 7)], 1);
        }
    }
    __syncthreads();
    for (int k = t; k < rbT; k += 256) {
        int c0 = cnt[k];
        if (c0) base[k] = bko[k] + atomicAdd(&gcur[k], c0);
        cnt[k] = 0;
    }
    __syncthreads();
    for (int u = 0; u < EPB / 256; ++u) {
        long long idx = start + u * 256 + t;
        if (idx < twoE) {
            int r = idx >= E;
            int e = (int)(idx - (long long)r * E);
            int s = edges[(size_t)r * 2 * E + e];
            int d = edges[(size_t)r * 2 * E + E + e];
            int rb = r * NBK + (d >> 7);
            int pos = atomicAdd(&cnt[rb], 1);
            staging[(size_t)base[rb] + pos] = make_uint2((unsigned)s, (unsigned)d);
        }
    }
}

// ---- radix pass D: per-bucket node hist/scan -> off[] and csr[] ----------
__global__ __launch_bounds__(256) void
bucket_csr_kernel(const uint2* __restrict__ staging, const int* __restrict__ bko,
                  int* __restrict__ csr, int* __restrict__ off,
                  int NBK, int N)
{
    __shared__ int hist[BW], excl[BW], cur[BW], sc[BW];
    const int rb = blockIdx.x;
    const int r = rb / NBK;
    const int b = rb % NBK;
    const int node0 = b * BW;
    const int nn = min(BW, N - node0);
    const int cbase = bko[rb];
    const int c = bko[rb + 1] - cbase;
    const int t = threadIdx.x;

    if (t < BW) { hist[t] = 0; cur[t] = 0; }
    __syncthreads();
    for (int k = t; k < c; k += 256)
        atomicAdd(&hist[(int)staging[(size_t)cbase + k].y - node0], 1);
    __syncthreads();
    if (t < BW) sc[t] = hist[t];
    __syncthreads();
    for (int s = 1; s < BW; s <<= 1) {
        int v = (t < BW && t >= s) ? sc[t - s] : 0;
        __syncthreads();
        if (t < BW) sc[t] += v;
        __syncthreads();
    }
    if (t < BW) excl[t] = sc[t] - hist[t];
    if (t < nn) off[(size_t)r * N + node0 + t] = cbase + excl[t];
    __syncthreads();
    for (int k = t; k < c; k += 256) {
        uint2 pr = staging[(size_t)cbase + k];
        int l = (int)pr.y - node0;
        int pos = atomicAdd(&cur[l], 1);
        csr[(size_t)cbase + excl[l] + pos] = (int)pr.x;
    }
}

// ---- f32 -> bf16 --------------------------------------------------------
__global__ void cvt_kernel(const float* __restrict__ in,
                           unsigned short* __restrict__ o, int n4)
{
    int t = blockIdx.x * blockDim.x + threadIdx.x;
    if (t >= n4) return;
    float4 v = ((const float4*)in)[t];
    ushort4 r;
    r.x = f2bf(v.x); r.y = f2bf(v.y); r.z = f2bf(v.z); r.w = f2bf(v.w);
    ((ushort4*)o)[t] = r;
}

// ---- weight prep: combined-Wself / Wn -> bf16 W^T rows, biases ----------
__global__ void prep_kernel(const float* __restrict__ Ws1, const float* __restrict__ Wn1,
                            const float* __restrict__ b1,
                            const float* __restrict__ Ws2, const float* __restrict__ Wn2,
                            const float* __restrict__ b2,
                            unsigned short* __restrict__ WT1z, unsigned short* __restrict__ WT1a,
                            unsigned short* __restrict__ WT1b, float* __restrict__ bc1,
                            unsigned short* __restrict__ WT2z, unsigned short* __restrict__ WT2a,
                            unsigned short* __restrict__ WT2b, float* __restrict__ bc2)
{
    int t = blockIdx.x * blockDim.x + threadIdx.x;
    if (t < 16384) {                 // layer 1: [n][k] <- [k][n], n,k < 128
        int n = t >> 7, k = t & 127;
        int in = k * 128 + n;
        WT1z[t] = f2bf(Ws1[in] + Ws1[16384 + in]);
        WT1a[t] = f2bf(Wn1[in]);
        WT1b[t] = f2bf(Wn1[16384 + in]);
    }
    if (t < 8192) {                  // layer 2: n < 64, k < 128
        int n = t >> 7, k = t & 127;
        int in = k * 64 + n;
        WT2z[t] = f2bf(Ws2[in] + Ws2[8192 + in]);
        WT2a[t] = f2bf(Wn2[in]);
        WT2b[t] = f2bf(Wn2[8192 + in]);
    }
    if (t < 128) bc1[t] = b1[t] + b1[128 + t];
    if (t < 64)  bc2[t] = b2[t] + b2[64 + t];
}

// ---- MFMA GEMM: blockIdx.y = sel in {z (f32,+bias), ya, yb (bf16)} ------
// A bf16 [N,128]; WT* bf16 [BN,128] (W^T rows). Block=256 (4 waves), each
// wave: 16 rows x BN cols via 16x16x32 MFMA, K=128 in 4 steps.
template<int BN>
__global__ __launch_bounds__(256) void
gemm_mfma_kernel(const unsigned short* __restrict__ Ab,
                 const unsigned short* __restrict__ WTz,
                 const unsigned short* __restrict__ WTa,
                 const unsigned short* __restrict__ WTb,
                 const float* __restrict__ bias,
                 float* __restrict__ zf,
                 unsigned short* __restrict__ ya, unsigned short* __restrict__ yb,
                 int N)
{
    constexpr int NT = BN / 16;
    __shared__ float eb[64][BN + 1];

    const int tid = threadIdx.x;
    const int wave = tid >> 6;
    const int lane = tid & 63;
    const int m = lane & 15;
    const int quad = lane >> 4;
    const int sel = blockIdx.y;
    const unsigned short* WT = (sel == 0) ? WTz : ((sel == 1) ? WTa : WTb);

    floatx4 acc[NT];
    const floatx4 z4 = {0.f, 0.f, 0.f, 0.f};
#pragma unroll
    for (int t = 0; t < NT; ++t) acc[t] = z4;

    int arow = blockIdx.x * 64 + wave * 16 + m;
    if (arow >= N) arow = N - 1;
    const unsigned short* aptr = Ab + (size_t)arow * 128 + quad * 8;

#pragma unroll
    for (int s = 0; s < 4; ++s) {
        bf16x8 a = *(const bf16x8*)(aptr + s * 32);
#pragma unroll
        for (int t = 0; t < NT; ++t) {
            bf16x8 b = *(const bf16x8*)(WT + (size_t)(t * 16 + m) * 128 + s * 32 + quad * 8);
            acc[t] = __builtin_amdgcn_mfma_f32_16x16x32_bf16(a, b, acc[t], 0, 0, 0);
        }
    }

    // C/D: col = lane&15, row = quad*4 + reg  -> LDS transpose
#pragma unroll
    for (int t = 0; t < NT; ++t)
#pragma unroll
        for (int i = 0; i < 4; ++i)
            eb[wave * 16 + quad * 4 + i][t * 16 + m] = acc[t][i];
    __syncthreads();

#pragma unroll
    for (int j = 0; j < 4; ++j) {
        int lr = wave * 16 + j * 4 + quad;
        int grow = blockIdx.x * 64 + lr;
        if (grow < N) {
#pragma unroll
            for (int i = 0; i < BN / 64; ++i) {
                int c0 = (i * 16 + m) * 4;
                float v0 = eb[lr][c0 + 0], v1 = eb[lr][c0 + 1];
                float v2 = eb[lr][c0 + 2], v3 = eb[lr][c0 + 3];
                if (sel == 0) {
                    float4 o;
                    o.x = v0 + bias[c0 + 0];
                    o.y = v1 + bias[c0 + 1];
                    o.z = v2 + bias[c0 + 2];
                    o.w = v3 + bias[c0 + 3];
                    *(float4*)(zf + (size_t)grow * BN + c0) = o;
                } else {
                    unsigned short* ob = (sel == 1) ? ya : yb;
                    ushort4 u;
                    u.x = f2bf(v0); u.y = f2bf(v1); u.z = f2bf(v2); u.w = f2bf(v3);
                    *(ushort4*)(ob + (size_t)grow * BN + c0) = u;
                }
            }
        }
    }
}

// ---- agg L1: wave per node, 128 cols, unroll x8 --------------------------
__global__ __launch_bounds__(256) void
agg1_kernel(const unsigned short* __restrict__ y0,
            const unsigned short* __restrict__ y1,
            const float* __restrict__ z1,
            const int* __restrict__ csr, const int* __restrict__ off,
            unsigned short* __restrict__ h1b, int N, int twoE)
{
    int w = blockIdx.x * 4 + (threadIdx.x >> 6);
    int lane = threadIdx.x & 63;
    if (w >= N) return;
    const int col = lane * 2;

    float sx0 = 0.f, sy0 = 0.f, sx1 = 0.f, sy1 = 0.f;
    int o0 = off[w], o1 = off[w + 1];
    int d0 = o1 - o0;
    int j = o0;
    for (; j + 7 < o1; j += 8) {
        int s0 = csr[j], s1 = csr[j + 1], s2 = csr[j + 2], s3 = csr[j + 3];
        int s4 = csr[j + 4], s5 = csr[j + 5], s6 = csr[j + 6], s7 = csr[j + 7];
        unsigned a0 = *(const unsigned*)(y0 + (size_t)s0 * 128 + col);
        unsigned a1 = *(const unsigned*)(y0 + (size_t)s1 * 128 + col);
        unsigned a2 = *(const unsigned*)(y0 + (size_t)s2 * 128 + col);
        unsigned a3 = *(const unsigned*)(y0 + (size_t)s3 * 128 + col);
        unsigned a4 = *(const unsigned*)(y0 + (size_t)s4 * 128 + col);
        unsigned a5 = *(const unsigned*)(y0 + (size_t)s5 * 128 + col);
        unsigned a6 = *(const unsigned*)(y0 + (size_t)s6 * 128 + col);
        unsigned a7 = *(const unsigned*)(y0 + (size_t)s7 * 128 + col);
        sx0 += ((bflo(a0) + bflo(a1)) + (bflo(a2) + bflo(a3))) +
               ((bflo(a4) + bflo(a5)) + (bflo(a6) + bflo(a7)));
        sy0 += ((bfhi(a0) + bfhi(a1)) + (bfhi(a2) + bfhi(a3))) +
               ((bfhi(a4) + bfhi(a5)) + (bfhi(a6) + bfhi(a7)));
    }
    for (; j < o1; ++j) {
        unsigned a = *(const unsigned*)(y0 + (size_t)csr[j] * 128 + col);
        sx0 += bflo(a); sy0 += bfhi(a);
    }
    int p = N + w;
    o0 = off[p];
    o1 = (p + 1 < 2 * N) ? off[p + 1] : twoE;
    int d1 = o1 - o0;
    j = o0;
    for (; j + 7 < o1; j += 8) {
        int s0 = csr[j], s1 = csr[j + 1], s2 = csr[j + 2], s3 = csr[j + 3];
        int s4 = csr[j + 4], s5 = csr[j + 5], s6 = csr[j + 6], s7 = csr[j + 7];
        unsigned a0 = *(const unsigned*)(y1 + (size_t)s0 * 128 + col);
        unsigned a1 = *(const unsigned*)(y1 + (size_t)s1 * 128 + col);
        unsigned a2 = *(const unsigned*)(y1 + (size_t)s2 * 128 + col);
        unsigned a3 = *(const unsigned*)(y1 + (size_t)s3 * 128 + col);
        unsigned a4 = *(const unsigned*)(y1 + (size_t)s4 * 128 + col);
        unsigned a5 = *(const unsigned*)(y1 + (size_t)s5 * 128 + col);
        unsigned a6 = *(const unsigned*)(y1 + (size_t)s6 * 128 + col);
        unsigned a7 = *(const unsigned*)(y1 + (size_t)s7 * 128 + col);
        sx1 += ((bflo(a0) + bflo(a1)) + (bflo(a2) + bflo(a3))) +
               ((bflo(a4) + bflo(a5)) + (bflo(a6) + bflo(a7)));
        sy1 += ((bfhi(a0) + bfhi(a1)) + (bfhi(a2) + bfhi(a3))) +
               ((bfhi(a4) + bfhi(a5)) + (bfhi(a6) + bfhi(a7)));
    }
    for (; j < o1; ++j) {
        unsigned a = *(const unsigned*)(y1 + (size_t)csr[j] * 128 + col);
        sx1 += bflo(a); sy1 += bfhi(a);
    }
    float inv0 = 1.0f / fmaxf((float)d0, 1.0f);
    float inv1 = 1.0f / fmaxf((float)d1, 1.0f);
    float2 z = *(const float2*)(z1 + (size_t)w * 128 + col);
    float hx = fmaxf(z.x + sx0 * inv0 + sx1 * inv1, 0.0f);
    float hy = fmaxf(z.y + sy0 * inv0 + sy1 * inv1, 0.0f);
    *(unsigned*)(h1b + (size_t)w * 128 + col) = pack2(hx, hy);
}

// ---- agg L2: wave per node, 64 cols, 2 edges/iter, unroll x4 -------------
__global__ __launch_bounds__(256) void
agg2_kernel(const unsigned short* __restrict__ t0,
            const unsigned short* __restrict__ t1,
            const float* __restrict__ z2,
            const int* __restrict__ csr, const int* __restrict__ off,
            unsigned short* __restrict__ h2b, int N, int twoE)
{
    int w = blockIdx.x * 4 + (threadIdx.x >> 6);
    int lane = threadIdx.x & 63;
    if (w >= N) return;
    const int half = lane >> 5;
    const int col = (lane & 31) * 2;

    float sx0 = 0.f, sy0 = 0.f, sx1 = 0.f, sy1 = 0.f;
    int o0 = off[w], o1 = off[w + 1];
    int d0 = o1 - o0;
    int j = o0 + half;
    for (; j + 6 < o1; j += 8) {
        int s0 = csr[j], s1 = csr[j + 2], s2 = csr[j + 4], s3 = csr[j + 6];
        unsigned a0 = *(const unsigned*)(t0 + (size_t)s0 * 64 + col);
        unsigned a1 = *(const unsigned*)(t0 + (size_t)s1 * 64 + col);
        unsigned a2 = *(const unsigned*)(t0 + (size_t)s2 * 64 + col);
        unsigned a3 = *(const unsigned*)(t0 + (size_t)s3 * 64 + col);
        sx0 += (bflo(a0) + bflo(a1)) + (bflo(a2) + bflo(a3));
        sy0 += (bfhi(a0) + bfhi(a1)) + (bfhi(a2) + bfhi(a3));
    }
    for (; j < o1; j += 2) {
        unsigned a = *(const unsigned*)(t0 + (size_t)csr[j] * 64 + col);
        sx0 += bflo(a); sy0 += bfhi(a);
    }
    int p = N + w;
    o0 = off[p];
    o1 = (p + 1 < 2 * N) ? off[p + 1] : twoE;
    int d1 = o1 - o0;
    j = o0 + half;
    for (; j + 6 < o1; j += 8) {
        int s0 = csr[j], s1 = csr[j + 2], s2 = csr[j + 4], s3 = csr[j + 6];
        unsigned a0 = *(const unsigned*)(t1 + (size_t)s0 * 64 + col);
        unsigned a1 = *(const unsigned*)(t1 + (size_t)s1 * 64 + col);
        unsigned a2 = *(const unsigned*)(t1 + (size_t)s2 * 64 + col);
        unsigned a3 = *(const unsigned*)(t1 + (size_t)s3 * 64 + col);
        sx1 += (bflo(a0) + bflo(a1)) + (bflo(a2) + bflo(a3));
        sy1 += (bfhi(a0) + bfhi(a1)) + (bfhi(a2) + bfhi(a3));
    }
    for (; j < o1; j += 2) {
        unsigned a = *(const unsigned*)(t1 + (size_t)csr[j] * 64 + col);
        sx1 += bflo(a); sy1 += bfhi(a);
    }
    sx0 += __shfl_xor(sx0, 32);
    sy0 += __shfl_xor(sy0, 32);
    sx1 += __shfl_xor(sx1, 32);
    sy1 += __shfl_xor(sy1, 32);
    if (half == 0) {
        float inv0 = 1.0f / fmaxf((float)d0, 1.0f);
        float inv1 = 1.0f / fmaxf((float)d1, 1.0f);
        float2 z = *(const float2*)(z2 + (size_t)w * 64 + col);
        float hx = z.x + sx0 * inv0 + sx1 * inv1;
        float hy = z.y + sy0 * inv0 + sy1 * inv1;
        *(unsigned*)(h2b + (size_t)w * 64 + col) = pack2(hx, hy);
    }
}

// ---- score: 8 lanes/edge, coalesced 128B rows, shfl reduce ---------------
__global__ __launch_bounds__(256) void
score_kernel(const unsigned short* __restrict__ h, // [N,64] bf16
             const int* __restrict__ src, const int* __restrict__ dst,
             float* __restrict__ out, int E)
{
    int t = blockIdx.x * blockDim.x + threadIdx.x;
    int e = t >> 3;
    int c = t & 7;
    if (e >= E) return;
    uint4 va = *(const uint4*)(h + (size_t)src[e] * 64 + c * 8);
    uint4 vb = *(const uint4*)(h + (size_t)dst[e] * 64 + c * 8);
    float s = 0.0f;
    s = fmaf(bflo(va.x), bflo(vb.x), s);
    s = fmaf(bfhi(va.x), bfhi(vb.x), s);
    s = fmaf(bflo(va.y), bflo(vb.y), s);
    s = fmaf(bfhi(va.y), bfhi(vb.y), s);
    s = fmaf(bflo(va.z), bflo(vb.z), s);
    s = fmaf(bfhi(va.z), bfhi(vb.z), s);
    s = fmaf(bflo(va.w), bflo(vb.w), s);
    s = fmaf(bfhi(va.w), bfhi(vb.w), s);
    s += __shfl_xor(s, 1);
    s += __shfl_xor(s, 2);
    s += __shfl_xor(s, 4);
    if (c == 0) out[e] = s;
}

extern "C" void kernel_launch(void* const* d_in, const int* in_sizes, int n_in,
                              void* d_out, int out_size, void* d_ws, size_t ws_size,
                              hipStream_t stream)
{
    const float* x     = (const float*)d_in[0];
    const int*   edges = (const int*)d_in[1];
    const int*   neg   = (const int*)d_in[2];
    const float* Wn1   = (const float*)d_in[3];
    const float* Ws1   = (const float*)d_in[4];
    const float* b1    = (const float*)d_in[5];
    const float* Wn2   = (const float*)d_in[6];
    const float* Ws2   = (const float*)d_in[7];
    const float* b2    = (const float*)d_in[8];
    float* out = (float*)d_out;

    const int Fin = 128, R = 2;
    const int N  = in_sizes[0] / Fin;        // 50000
    const int E  = in_sizes[1] / (R * 2);    // 800000
    const int En = in_sizes[2] / 2;          // 800000
    const int twoE = 2 * E;
    const int NBK = (N + BW - 1) / BW;       // 391
    const int rbT = 2 * NBK;

    // ---- workspace layout (aliases noted) ----
    float* ws = (float*)d_ws;
    float* z1 = ws;                                    // [N,128] f32 (staging alias; z2 reuses)
    unsigned short* y0  = (unsigned short*)(z1 + (size_t)N * 128);  // [N,128] bf16 (t0 reuses)
    unsigned short* y1  = y0 + (size_t)N * 128;        // [N,128] bf16 (t1 + h2b reuse)
    unsigned short* xb  = y1 + (size_t)N * 128;        // [N,128] bf16
    unsigned short* h1b = xb + (size_t)N * 128;        // [N,128] bf16
    unsigned short* WT1z = h1b + (size_t)N * 128;      // [128,128] bf16 W^T
    unsigned short* WT1a = WT1z + 16384;
    unsigned short* WT1b = WT1a + 16384;
    unsigned short* WT2z = WT1b + 16384;               // [64,128]
    unsigned short* WT2a = WT2z + 8192;
    unsigned short* WT2b = WT2a + 8192;
    float* bc1 = (float*)(WT2b + 8192);                // [128]
    float* bc2 = bc1 + 128;                            // [64]
    int* bcnt = (int*)(bc2 + 64);                      // [2*NBK_MAX]
    int* gcur = bcnt + 2 * NBK_MAX;                    // [2*NBK_MAX]
    int* bko  = gcur + 2 * NBK_MAX;                    // [2*NBK_MAX+1]
    int* off  = bko + 2 * NBK_MAX + 1;                 // [2N]
    int* csr  = off + (size_t)2 * N;                   // [2E]

    uint2* staging = (uint2*)z1;                       // [2E] pairs, dead before gemm1
    float* z2 = z1;                                    // [N,64] f32
    unsigned short* t0 = y0;                           // [N,64] bf16
    unsigned short* t1 = y1;                           // [N,64] bf16
    unsigned short* h2b = y1 + (size_t)N * 64;         // [N,64] bf16

    const int BS = 256;
    const int edge_blocks = (twoE + EPB - 1) / EPB;
    const int gx = (N + 63) / 64;

    // ---- CSR build (radix by dst bucket) ----
    hipMemsetAsync(bcnt, 0, (size_t)4 * NBK_MAX * sizeof(int), stream);
    bucket_count_kernel<<<edge_blocks, BS, 0, stream>>>(edges, bcnt, NBK, E);
    bucket_scan_kernel<<<1, 1024, 0, stream>>>(bcnt, bko, rbT, twoE);
    partition_kernel<<<edge_blocks, BS, 0, stream>>>(edges, bko, gcur, staging, NBK, E);
    bucket_csr_kernel<<<rbT, BS, 0, stream>>>(staging, bko, csr, off, NBK, N);

    // ---- prep ----
    cvt_kernel<<<(N * 32 + BS - 1) / BS, BS, 0, stream>>>(x, xb, N * 32);
    prep_kernel<<<(16384 + BS - 1) / BS, BS, 0, stream>>>(
        Ws1, Wn1, b1, Ws2, Wn2, b2,
        WT1z, WT1a, WT1b, bc1, WT2z, WT2a, WT2b, bc2);

    // ---- Layer 1: transform (MFMA) then aggregate ----
    {
        dim3 g(gx, 3);
        gemm_mfma_kernel<128><<<g, BS, 0, stream>>>(xb, WT1z, WT1a, WT1b, bc1,
                                                    z1, y0, y1, N);
    }
    agg1_kernel<<<(N + 3) / 4, BS, 0, stream>>>(y0, y1, z1, csr, off, h1b, N, twoE);

    // ---- Layer 2 ----
    {
        dim3 g(gx, 3);
        gemm_mfma_kernel<64><<<g, BS, 0, stream>>>(h1b, WT2z, WT2a, WT2b, bc2,
                                                   z2, t0, t1, N);
    }
    agg2_kernel<<<(N + 3) / 4, BS, 0, stream>>>(t0, t1, z2, csr, off, h2b, N, twoE);

    // ---- Scores ----
    score_kernel<<<(E * 8 + BS - 1) / BS, BS, 0, stream>>>(h2b, edges, edges + E, out, E);
    score_kernel<<<(En * 8 + BS - 1) / BS, BS, 0, stream>>>(h2b, neg, neg + En, out + E, En);
}